// Round 9
// baseline (599.021 us; speedup 1.0000x reference)
//
#include <hip/hip_runtime.h>

#define NHEADS 8
#define DIM 384
#define BB 4
#define HW 16384      // 128*128
#define CPH 48        // channels per head

typedef unsigned int u32;
typedef _Float16 f16x8 __attribute__((ext_vector_type(8)));
typedef _Float16 f16x4 __attribute__((ext_vector_type(4)));
typedef __attribute__((ext_vector_type(4))) float f32x4;

__device__ __forceinline__ float wave_min(float v) {
    #pragma unroll
    for (int off = 32; off; off >>= 1) v = fminf(v, __shfl_xor(v, off));
    return v;
}
__device__ __forceinline__ float wave_max(float v) {
    #pragma unroll
    for (int off = 32; off; off >>= 1) v = fmaxf(v, __shfl_xor(v, off));
    return v;
}
__device__ __forceinline__ float wave_sum(float v) {
    #pragma unroll
    for (int off = 32; off; off >>= 1) v += __shfl_xor(v, off);
    return v;
}

__device__ __forceinline__ u32 pack2h(float a, float b) {
    union { _Float16 h[2]; u32 u; } p;
    p.h[0] = (_Float16)a; p.h[1] = (_Float16)b;
    return p.u;
}

// ---------------- fp32 -> fp16 weight convert ----------------
__global__ void cvt_w(const float* __restrict__ a, _Float16* __restrict__ o, int n)
{
    const int i = blockIdx.x * 256 + threadIdx.x;
    if (i < n) o[i] = (_Float16)a[i];
}

// ---------------- x[b][c][n] fp32 -> xt[b][n][c] fp16, LDS-tiled ----------------
// Tile 64n x 192c. Reads: 256B-coalesced per wave per channel. Writes: fully
// linear 384B row-runs (4KB per block iteration) -- no scattered 16B sectors.
__global__ __launch_bounds__(256) void transpose_cvt(
    const float* __restrict__ x, _Float16* __restrict__ xt)
{
    const int n0 = blockIdx.x * 64;
    const int c0 = blockIdx.y * 192;
    const int b  = blockIdx.z;
    __shared__ u32 tile[64 * 97];            // [n][c/2], rows padded to 97 dwords
    const int t = threadIdx.x, w = t >> 6, l = t & 63;

    const float* xb = x + ((size_t)b * DIM + c0) * HW + n0 + l;
    #pragma unroll 4
    for (int j = 0; j < 24; ++j) {
        const int cc = j * 8 + w * 2;        // even, covers 0..190
        const float v0 = xb[(size_t)cc * HW];
        const float v1 = xb[(size_t)(cc + 1) * HW];
        tile[l * 97 + (cc >> 1)] = pack2h(v0, v1);
    }
    __syncthreads();

    _Float16* ob = xt + ((size_t)b * HW + n0) * DIM + c0;
    #pragma unroll
    for (int it = 0; it < 6; ++it) {
        const int elem = it * 2048 + t * 8;  // half index in 64x192 tile
        const int nl = elem / 192, col = elem % 192;
        const int base = nl * 97 + (col >> 1);
        u32 out4[4] = { tile[base], tile[base + 1], tile[base + 2], tile[base + 3] };
        *(uint4*)&ob[(size_t)nl * DIM + col] = *(const uint4*)out4;
    }
}

// ---------------- v~[b][c][n] fp16 -> vt[b][n][c] fp16, LDS-tiled ----------------
// Tile 128n x 192c. Reads: u32 (2 n) per lane, 256B-coalesced. Writes: linear.
__global__ __launch_bounds__(256) void transpose16(
    const _Float16* __restrict__ in, _Float16* __restrict__ ot)
{
    const int n0 = blockIdx.x * 128;
    const int c0 = blockIdx.y * 192;
    const int b  = blockIdx.z;
    __shared__ _Float16 tile[128 * 194];     // [n][c], rows padded to 194 halfs
    const int t = threadIdx.x, w = t >> 6, l = t & 63;

    const _Float16* ib = in + ((size_t)b * DIM + c0) * HW + n0 + 2 * l;
    #pragma unroll 4
    for (int j = 0; j < 48; ++j) {
        const int cc = j * 4 + w;            // covers 0..191
        union { u32 u; _Float16 h[2]; } v;
        v.u = *(const u32*)&ib[(size_t)cc * HW];
        tile[(2 * l) * 194 + cc]     = v.h[0];
        tile[(2 * l + 1) * 194 + cc] = v.h[1];
    }
    __syncthreads();

    _Float16* ob = ot + ((size_t)b * HW + n0) * DIM + c0;
    #pragma unroll
    for (int it = 0; it < 12; ++it) {
        const int elem = it * 2048 + t * 8;  // half index in 128x192 tile
        const int nl = elem / 192, col = elem % 192;
        const _Float16* src = &tile[nl * 194 + col];
        u32 out4[4];
        out4[0] = *(const u32*)&src[0];
        out4[1] = *(const u32*)&src[2];
        out4[2] = *(const u32*)&src[4];
        out4[3] = *(const u32*)&src[6];
        *(uint4*)&ob[(size_t)nl * DIM + col] = *(const uint4*)out4;
    }
}

// ---------------- fp16 MFMA GEMM, direct-fragment (no LDS, no barriers) --------
// Y[b][m][n] = sum_k W[b][m][k]*Xt[b][n][k].  Both operands K-contiguous, so each
// lane's MFMA fragment is a direct aligned 16B global load (gram_qk structure).
// Grid: x = mtiles*128 flat (ntiles = HW/128 = 128 fixed); bijective XCD swizzle,
// m-fastest, so the mtiles same-n blocks run on one XCD and share the B-tile in L2.
// wbs = per-batch W stride (elems, 0 = shared W); out_f32 selects epilogue type.
__global__ __launch_bounds__(256) void gemm_f16(
    const _Float16* __restrict__ W, const _Float16* __restrict__ Xt,
    void* __restrict__ Y, int out_f32, int wbs)
{
    const int nwg    = gridDim.x;          // mtiles * 128, multiple of 8
    const int mtiles = nwg >> 7;
    const int bid    = blockIdx.x;
    const int wg     = (bid & 7) * (nwg >> 3) + (bid >> 3);   // bijective XCD swizzle
    const int m0     = (wg % mtiles) * 128;
    const int n0     = (wg / mtiles) * 128;
    const int b      = blockIdx.z;
    const int M      = mtiles * 128;

    const int t = threadIdx.x;
    const int w = t >> 6;
    const int l = t & 63;
    const int wm = (w >> 1) * 64, wn = (w & 1) * 64;
    const int fr = l & 15, fk = (l >> 4) * 8;

    // per-lane fragment base rows (identical addresses to the old LDS-staged path)
    const _Float16* Ab = W + (size_t)b * wbs + ((size_t)m0 + wm + fr) * DIM + fk;
    const _Float16* Bb = Xt + ((size_t)b * HW + n0 + wn + fr) * DIM + fk;

    f32x4 acc[4][4];
    #pragma unroll
    for (int i = 0; i < 4; ++i)
        #pragma unroll
        for (int j = 0; j < 4; ++j)
            acc[i][j] = (f32x4){0.f, 0.f, 0.f, 0.f};

    #pragma unroll 4
    for (int k0 = 0; k0 < DIM; k0 += 32) {
        f16x8 af[4], bf[4];
        #pragma unroll
        for (int mi = 0; mi < 4; ++mi)
            af[mi] = *(const f16x8*)&Ab[(size_t)(mi * 16) * DIM + k0];
        #pragma unroll
        for (int ni = 0; ni < 4; ++ni)
            bf[ni] = *(const f16x8*)&Bb[(size_t)(ni * 16) * DIM + k0];
        #pragma unroll
        for (int mi = 0; mi < 4; ++mi)
            #pragma unroll
            for (int ni = 0; ni < 4; ++ni)
                acc[mi][ni] = __builtin_amdgcn_mfma_f32_16x16x32_f16(
                    af[mi], bf[ni], acc[mi][ni], 0, 0, 0);
    }

    const int er = (l >> 4) * 4;   // C/D: col=l&15, row=(l>>4)*4+r
    if (out_f32) {
        float* Yp = (float*)Y + (size_t)b * M * HW;
        #pragma unroll
        for (int mi = 0; mi < 4; ++mi)
            #pragma unroll
            for (int ni = 0; ni < 4; ++ni)
                #pragma unroll
                for (int r = 0; r < 4; ++r)
                    Yp[(size_t)(m0 + wm + mi * 16 + er + r) * HW + n0 + wn + ni * 16 + fr]
                        = acc[mi][ni][r];
    } else {
        _Float16* Yp = (_Float16*)Y + (size_t)b * M * HW;
        #pragma unroll
        for (int mi = 0; mi < 4; ++mi)
            #pragma unroll
            for (int ni = 0; ni < 4; ++ni)
                #pragma unroll
                for (int r = 0; r < 4; ++r)
                    Yp[(size_t)(m0 + wm + mi * 16 + er + r) * HW + n0 + wn + ni * 16 + fr]
                        = (_Float16)acc[mi][ni][r];
    }
}

// ------- depthwise 3x3 SAME over all 1152 qkv planes, fp16 io, LDS-tiled -------
// plane p = b*1152 + c; group g = c/384 selects output buffer (q->oq, k->ok, v->ov).
// ss accumulate for q,k groups only (c < 768) -- block-uniform branch.
__global__ __launch_bounds__(256) void dwconv_all(
    const _Float16* __restrict__ in, const float* __restrict__ w9,
    _Float16* __restrict__ oq, _Float16* __restrict__ ok_,
    _Float16* __restrict__ ov, float* __restrict__ ss)
{
    const int j  = blockIdx.x & 3;
    const int p  = blockIdx.x >> 2;        // b*1152 + c
    const int c  = p % 1152;
    const int b  = p / 1152;
    const int r0 = j * 32;

    __shared__ __align__(16) _Float16 tile[34 * 136 + 8];   // 4632 halfs
    const int t = threadIdx.x;

    const uint4 z4 = make_uint4(0, 0, 0, 0);
    for (int i = t; i < 579; i += 256)
        *(uint4*)&tile[i * 8] = z4;
    __syncthreads();

    const _Float16* ip = in + (size_t)p * HW;
    for (int cc = t; cc < 34 * 16; cc += 256) {
        const int i = cc >> 4, seg = cc & 15;
        const int g = r0 - 1 + i;
        if ((unsigned)g < 128u)
            *(f16x8*)&tile[i * 136 + 8 + seg * 8] = *(const f16x8*)&ip[g * 128 + seg * 8];
    }

    float w[9];
    #pragma unroll
    for (int i = 0; i < 9; ++i) w[i] = w9[c * 9 + i];
    __syncthreads();

    const int yr = t >> 3;            // 0..31
    const int xc = (t & 7) * 16;      // 0..112

    float acc[16];
    #pragma unroll
    for (int cc = 0; cc < 16; ++cc) acc[cc] = 0.f;

    #pragma unroll
    for (int dy = 0; dy < 3; ++dy) {
        const _Float16* rp = &tile[(yr + dy) * 136 + xc];
        const f16x8 v0 = *(const f16x8*)&rp[0];
        const f16x8 v1 = *(const f16x8*)&rp[8];
        const f16x8 v2 = *(const f16x8*)&rp[16];
        const f16x8 v3 = *(const f16x8*)&rp[24];
        float rv[18];
        #pragma unroll
        for (int i = 0; i < 18; ++i) {
            const int idx = 7 + i;    // LDS cols xc+7 .. xc+24 = global cols xc-1 .. xc+16
            const _Float16 h = (idx < 8)  ? v0[idx]
                             : (idx < 16) ? v1[idx - 8]
                             : (idx < 24) ? v2[idx - 16]
                                          : v3[idx - 24];
            rv[i] = (float)h;
        }
        const float w0 = w[dy * 3 + 0], w1 = w[dy * 3 + 1], w2 = w[dy * 3 + 2];
        #pragma unroll
        for (int cc = 0; cc < 16; ++cc) {
            acc[cc] = fmaf(rv[cc],     w0, acc[cc]);
            acc[cc] = fmaf(rv[cc + 1], w1, acc[cc]);
            acc[cc] = fmaf(rv[cc + 2], w2, acc[cc]);
        }
    }

    alignas(16) _Float16 oh[16];
    float ssum = 0.f;
    #pragma unroll
    for (int cc = 0; cc < 16; ++cc) {
        oh[cc] = (_Float16)acc[cc];
        ssum = fmaf(acc[cc], acc[cc], ssum);
    }
    const int grp = c / 384;
    const int cl  = c - grp * 384;
    _Float16* obase = (grp == 0) ? oq : (grp == 1) ? ok_ : ov;
    _Float16* op = obase + ((size_t)b * DIM + cl) * HW + (r0 + yr) * 128 + xc;
    *(f16x8*)&op[0] = *(const f16x8*)&oh[0];
    *(f16x8*)&op[8] = *(const f16x8*)&oh[8];

    if (c < 768) {                         // q,k groups: sumsq for normalization
        __syncthreads();                   // all tile reads done; reuse LDS
        float* red = (float*)tile;
        red[t] = ssum;
        __syncthreads();
        for (int s = 128; s > 0; s >>= 1) {
            if (t < s) red[t] += red[t + s];
            __syncthreads();
        }
        if (t == 0) atomicAdd(&ss[b * (2 * DIM) + c], red[0]);
    }
}

// ------------- raw gram G[b,h,c,d] = sum_n q[c,n]*k[d,n], fp16 in, MFMA split-K -------------
#define GNC 1024
__global__ __launch_bounds__(256) void gram_qk(
    const _Float16* __restrict__ qA, const _Float16* __restrict__ kA,
    float* __restrict__ G)
{
    const int n0 = blockIdx.x * GNC;
    const int h  = blockIdx.y;
    const int b  = blockIdx.z;
    const _Float16* qb = qA + ((size_t)b * DIM + h * CPH) * HW + n0;
    const _Float16* kb = kA + ((size_t)b * DIM + h * CPH) * HW + n0;

    const int t = threadIdx.x;
    const int w = t >> 6, l = t & 63;
    const int fr = l & 15, fk = (l >> 4) * 8;

    f32x4 acc[3][3];
    #pragma unroll
    for (int i = 0; i < 3; ++i)
        #pragma unroll
        for (int j = 0; j < 3; ++j)
            acc[i][j] = (f32x4){0.f, 0.f, 0.f, 0.f};

    const int nbase = w * (GNC / 4);    // 256 cols of n per wave
    #pragma unroll 4
    for (int nn = 0; nn < GNC / 4; nn += 32) {
        f16x8 qf[3], kf[3];
        #pragma unroll
        for (int i = 0; i < 3; ++i) {
            const size_t off = (size_t)(i * 16 + fr) * HW + nbase + nn + fk;
            qf[i] = *(const f16x8*)&qb[off];
            kf[i] = *(const f16x8*)&kb[off];
        }
        #pragma unroll
        for (int i = 0; i < 3; ++i)
            #pragma unroll
            for (int j = 0; j < 3; ++j)
                acc[i][j] = __builtin_amdgcn_mfma_f32_16x16x32_f16(
                    qf[i], kf[j], acc[i][j], 0, 0, 0);
    }

    // block-level reduce across the 4 waves in LDS, then one atomicAdd per element
    __shared__ float red[4][CPH * CPH];   // 36 KB
    const int er = (l >> 4) * 4;
    #pragma unroll
    for (int i = 0; i < 3; ++i)
        #pragma unroll
        for (int j = 0; j < 3; ++j)
            #pragma unroll
            for (int r = 0; r < 4; ++r)
                red[w][(i * 16 + er + r) * CPH + j * 16 + fr] = acc[i][j][r];
    __syncthreads();

    float* Gp = G + ((size_t)(b * NHEADS + h)) * CPH * CPH;
    for (int i = t; i < CPH * CPH; i += 256)
        atomicAdd(&Gp[i], red[0][i] + red[1][i] + red[2][i] + red[3][i]);
}

// ------------- normalize + 4x top-k softmax combined into one P (one wave per row) -------------
__global__ __launch_bounds__(64) void topk_combine(
    const float* __restrict__ G, const float* __restrict__ ss,
    const float* __restrict__ temp,
    const float* __restrict__ a1, const float* __restrict__ a2,
    const float* __restrict__ a3, const float* __restrict__ a4,
    float* __restrict__ P)
{
    const int row = blockIdx.x;           // bh*48 + r
    const int bh  = row / CPH;
    const int r   = row - bh * CPH;
    const int b = bh >> 3, h = bh & 7;
    const int l = threadIdx.x;

    const float tpr = temp[h];
    const float* ssb = ss + b * (2 * DIM);
    const float invq = 1.f / sqrtf(ssb[h * CPH + r]);

    float att = -3.0e38f;
    if (l < CPH)
        att = G[(size_t)row * CPH + l] * invq * (1.f / sqrtf(ssb[DIM + h * CPH + l])) * tpr;

    int cnt = 0;                          // # strictly greater
    #pragma unroll
    for (int i = 0; i < CPH; ++i)
        cnt += (__shfl(att, i) > att) ? 1 : 0;

    const float mx   = wave_max(att);
    const float thr0 = wave_min((l < CPH && cnt < 24) ? att : 3.0e38f);
    const float thr1 = wave_min((l < CPH && cnt < 32) ? att : 3.0e38f);
    const float thr2 = wave_min((l < CPH && cnt < 36) ? att : 3.0e38f);
    const float thr3 = wave_min((l < CPH && cnt < 38) ? att : 3.0e38f);

    const float e = (l < CPH) ? expf(att - mx) : 0.f;
    const float Z0 = wave_sum(att >= thr0 ? e : 0.f);
    const float Z1 = wave_sum(att >= thr1 ? e : 0.f);
    const float Z2 = wave_sum(att >= thr2 ? e : 0.f);
    const float Z3 = wave_sum(att >= thr3 ? e : 0.f);

    const float w0 = a1[0] / Z0, w1 = a2[0] / Z1, w2 = a3[0] / Z2, w3 = a4[0] / Z3;
    float pv = 0.f;
    if (att >= thr0) pv += w0 * e;
    if (att >= thr1) pv += w1 * e;
    if (att >= thr2) pv += w2 * e;
    if (att >= thr3) pv += w3 * e;
    if (l < CPH) P[(size_t)row * CPH + l] = pv;
}

// ------------- fused projection weight: Wf[b][o][h*48+d] = sum_c pw[o][h*48+c]*P[b,h,c,d] ----
// grid (DIM/48, NHEADS, nb) = 256 blocks; P tile + pw tile staged in LDS,
// 9 independent LDS-fed dot products per thread. Same c-summation order as before
// (bit-identical Wf).
__global__ __launch_bounds__(256) void fuse_pw(
    const float* __restrict__ pw, const float* __restrict__ P,
    _Float16* __restrict__ Wf)
{
    const int o0 = blockIdx.x * CPH;
    const int h  = blockIdx.y;
    const int b  = blockIdx.z;
    const int t  = threadIdx.x;

    __shared__ float sP[CPH][CPH];        // [c][d]
    __shared__ float sW[CPH][CPH + 1];    // [o][c]
    for (int i = t; i < CPH * CPH; i += 256) {
        const int r = i / CPH, cc = i % CPH;
        sP[r][cc] = P[((size_t)(b * NHEADS + h)) * CPH * CPH + i];
        sW[r][cc] = pw[(size_t)(o0 + r) * DIM + h * CPH + cc];
    }
    __syncthreads();

    for (int i = t; i < CPH * CPH; i += 256) {
        const int o = i / CPH, d = i % CPH;
        float s = 0.f;
        #pragma unroll
        for (int c = 0; c < CPH; ++c)
            s = fmaf(sW[o][c], sP[c][d], s);
        Wf[((size_t)b * DIM + o0 + o) * DIM + h * CPH + d] = (_Float16)s;
    }
}

extern "C" void kernel_launch(void* const* d_in, const int* in_sizes, int n_in,
                              void* d_out, int out_size, void* d_ws, size_t ws_size,
                              hipStream_t stream)
{
    const float* x      = (const float*)d_in[0];
    const float* qkv_w  = (const float*)d_in[1];
    const float* dw_w   = (const float*)d_in[2];
    const float* proj_w = (const float*)d_in[3];
    const float* temp   = (const float*)d_in[4];
    const float* a1 = (const float*)d_in[5];
    const float* a2 = (const float*)d_in[6];
    const float* a3 = (const float*)d_in[7];
    const float* a4 = (const float*)d_in[8];
    float* out = (float*)d_out;

    const size_t PBE = (size_t)HW * DIM;        // per-batch elems (6,291,456)
    const size_t WQE = (size_t)1152 * 384;
    const size_t WPE = (size_t)384 * 384;

    // regions: A(1) + C(3) + D(1) + E(1) + F(1) = 7*PBE fp16 per batch
    auto need_for = [&](size_t nb) -> size_t {
        return nb * PBE * 2 * 7 + (WQE + nb * WPE) * 2
             + (nb * 768 + 2 * nb * NHEADS * CPH * CPH) * 4;
    };

    int nb, npass;
    if      (ws_size >= need_for(4)) { nb = 4; npass = 1; }
    else if (ws_size >= need_for(2)) { nb = 2; npass = 2; }
    else if (ws_size >= need_for(1)) { nb = 1; npass = 4; }
    else return;

    _Float16* A  = (_Float16*)d_ws;             // xt -> vt [nb][HW][384]
    _Float16* C  = A + (size_t)nb * PBE;        // raw qkv [nb][1152][HW]
    _Float16* D  = C + (size_t)3 * nb * PBE;    // q~
    _Float16* E  = D + (size_t)nb * PBE;        // k~
    _Float16* F  = E + (size_t)nb * PBE;        // v~
    _Float16* wq = F + (size_t)nb * PBE;        // qkv_w fp16 [1152][384]
    _Float16* Wf = wq + WQE;                    // fused proj weight [nb][384][384]
    float* buf_ss = (float*)(Wf + (size_t)nb * WPE);          // [nb][768]
    float* buf_G  = buf_ss + (size_t)nb * 768;                // [nb][8][48][48]
    float* buf_P  = buf_G + (size_t)nb * NHEADS * CPH * CPH;

    cvt_w<<<dim3((1152 * 384 + 255) / 256), 256, 0, stream>>>(qkv_w, wq, 1152 * 384);

    for (int p = 0; p < npass; ++p) {
        const int b0 = p * nb;
        const float* xp   = x   + (size_t)b0 * PBE;
        float*       outp = out + (size_t)b0 * PBE;

        transpose_cvt<<<dim3(HW / 64, 2, nb), 256, 0, stream>>>(xp, A);
        // zero ss + G (contiguous) — dwconv and gram accumulate atomically
        hipMemsetAsync(buf_ss, 0,
                       ((size_t)nb * 768 + (size_t)nb * NHEADS * CPH * CPH) * sizeof(float),
                       stream);

        // merged qkv GEMM: [1152][384] @ xt -> C ; flat grid = mtiles(9) * ntiles(128)
        gemm_f16<<<dim3((1152 / 128) * (HW / 128), 1, nb), 256, 0, stream>>>(wq, A, C, 0, 0);

        // merged depthwise over all 1152 planes; q->D, k->E, v->F; ss for q,k
        dwconv_all<<<dim3(nb * 1152 * 4), 256, 0, stream>>>(C, dw_w, D, E, F, buf_ss);

        gram_qk<<<dim3(HW / GNC, NHEADS, nb), 256, 0, stream>>>(D, E, buf_G);
        topk_combine<<<dim3(nb * NHEADS * CPH), 64, 0, stream>>>(
            buf_G, buf_ss, temp, a1, a2, a3, a4, buf_P);

        // fused proj weight (pw @ P per head/batch)
        fuse_pw<<<dim3(DIM / CPH, NHEADS, nb), 256, 0, stream>>>(proj_w, buf_P, Wf);

        // v~ -> vt (Xt layout); xt in A dead after merged GEMM
        transpose16<<<dim3(HW / 128, 2, nb), 256, 0, stream>>>(F, A);

        // fused PV+proj: out = Wf_b @ vt, fp32 out ; flat grid = 3 * 128
        gemm_f16<<<dim3((DIM / 128) * (HW / 128), 1, nb), 256, 0, stream>>>(Wf, A, outp, 1, (int)WPE);
    }
}

// Round 12
// 442.244 us; speedup vs baseline: 1.3545x; 1.3545x over previous
//
#include <hip/hip_runtime.h>

#define NHEADS 8
#define DIM 384
#define BB 4
#define HW 16384      // 128*128
#define CPH 48        // channels per head

typedef unsigned int u32;
typedef _Float16 f16x8 __attribute__((ext_vector_type(8)));
typedef _Float16 f16x4 __attribute__((ext_vector_type(4)));
typedef __attribute__((ext_vector_type(4))) float f32x4;

__device__ __forceinline__ float wave_min(float v) {
    #pragma unroll
    for (int off = 32; off; off >>= 1) v = fminf(v, __shfl_xor(v, off));
    return v;
}
__device__ __forceinline__ float wave_max(float v) {
    #pragma unroll
    for (int off = 32; off; off >>= 1) v = fmaxf(v, __shfl_xor(v, off));
    return v;
}
__device__ __forceinline__ float wave_sum(float v) {
    #pragma unroll
    for (int off = 32; off; off >>= 1) v += __shfl_xor(v, off);
    return v;
}

__device__ __forceinline__ u32 pack2h(float a, float b) {
    union { _Float16 h[2]; u32 u; } p;
    p.h[0] = (_Float16)a; p.h[1] = (_Float16)b;
    return p.u;
}

// async global->LDS, 16B per lane; LDS dest = wave-uniform base + lane*16
#define GLOBAL_TO_LDS16(gsrc, ldst)                                           \
    __builtin_amdgcn_global_load_lds(                                         \
        (const __attribute__((address_space(1))) u32*)(gsrc),                 \
        (__attribute__((address_space(3))) u32*)(ldst), 16, 0, 0)

// ---------------- fp32 -> fp16 weight convert ----------------
__global__ void cvt_w(const float* __restrict__ a, _Float16* __restrict__ o, int n)
{
    const int i = blockIdx.x * 256 + threadIdx.x;
    if (i < n) o[i] = (_Float16)a[i];
}

// ---------------- x[b][c][n] fp32 -> xt[b][n][c] fp16, LDS-tiled ----------------
// Tile 64n x 192c. Reads: 256B-coalesced per wave per channel. Writes: fully
// linear 384B row-runs (4KB per block iteration) -- no scattered 16B sectors.
__global__ __launch_bounds__(256) void transpose_cvt(
    const float* __restrict__ x, _Float16* __restrict__ xt)
{
    const int n0 = blockIdx.x * 64;
    const int c0 = blockIdx.y * 192;
    const int b  = blockIdx.z;
    __shared__ u32 tile[64 * 97];            // [n][c/2], rows padded to 97 dwords
    const int t = threadIdx.x, w = t >> 6, l = t & 63;

    const float* xb = x + ((size_t)b * DIM + c0) * HW + n0 + l;
    #pragma unroll 4
    for (int j = 0; j < 24; ++j) {
        const int cc = j * 8 + w * 2;        // even, covers 0..190
        const float v0 = xb[(size_t)cc * HW];
        const float v1 = xb[(size_t)(cc + 1) * HW];
        tile[l * 97 + (cc >> 1)] = pack2h(v0, v1);
    }
    __syncthreads();

    _Float16* ob = xt + ((size_t)b * HW + n0) * DIM + c0;
    #pragma unroll
    for (int it = 0; it < 6; ++it) {
        const int elem = it * 2048 + t * 8;  // half index in 64x192 tile
        const int nl = elem / 192, col = elem % 192;
        const int base = nl * 97 + (col >> 1);
        u32 out4[4] = { tile[base], tile[base + 1], tile[base + 2], tile[base + 3] };
        *(uint4*)&ob[(size_t)nl * DIM + col] = *(const uint4*)out4;
    }
}

// ---------------- v~[b][c][n] fp16 -> vt[b][n][c] fp16, LDS-tiled ----------------
// Tile 128n x 192c. Reads: u32 (2 n) per lane, 256B-coalesced. Writes: linear.
__global__ __launch_bounds__(256) void transpose16(
    const _Float16* __restrict__ in, _Float16* __restrict__ ot)
{
    const int n0 = blockIdx.x * 128;
    const int c0 = blockIdx.y * 192;
    const int b  = blockIdx.z;
    __shared__ _Float16 tile[128 * 194];     // [n][c], rows padded to 194 halfs
    const int t = threadIdx.x, w = t >> 6, l = t & 63;

    const _Float16* ib = in + ((size_t)b * DIM + c0) * HW + n0 + 2 * l;
    #pragma unroll 4
    for (int j = 0; j < 48; ++j) {
        const int cc = j * 4 + w;            // covers 0..191
        union { u32 u; _Float16 h[2]; } v;
        v.u = *(const u32*)&ib[(size_t)cc * HW];
        tile[(2 * l) * 194 + cc]     = v.h[0];
        tile[(2 * l + 1) * 194 + cc] = v.h[1];
    }
    __syncthreads();

    _Float16* ob = ot + ((size_t)b * HW + n0) * DIM + c0;
    #pragma unroll
    for (int it = 0; it < 12; ++it) {
        const int elem = it * 2048 + t * 8;  // half index in 128x192 tile
        const int nl = elem / 192, col = elem % 192;
        const _Float16* src = &tile[nl * 194 + col];
        u32 out4[4];
        out4[0] = *(const u32*)&src[0];
        out4[1] = *(const u32*)&src[2];
        out4[2] = *(const u32*)&src[4];
        out4[3] = *(const u32*)&src[6];
        *(uint4*)&ob[(size_t)nl * DIM + col] = *(const uint4*)out4;
    }
}

// ---------------- fp16 MFMA GEMM: Y[b][m][n] = sum_k W[b][m][k]*Xt[b][n][k] --------
// M = gridDim.y*128 (per-batch Y stride). K = DIM. Y: fp16 or fp32.
// wbs = per-batch W stride (elems), 0 = shared W.
// R7-verified single-buffer structure, BK=64 as two 32-k panels: half the
// barrier drains (6 K-iterations instead of 12), 32 MFMA per barrier, identical
// per-lane staging addresses and LDS bank behavior to the verified BK=32 kernel.
__global__ __launch_bounds__(256) void gemm_f16(
    const _Float16* __restrict__ W, const _Float16* __restrict__ Xt,
    void* __restrict__ Y, int out_f32, int wbs)
{
    const int n0 = blockIdx.x * 128;
    const int m0 = blockIdx.y * 128;
    const int b  = blockIdx.z;
    const int M  = gridDim.y * 128;

    __shared__ _Float16 sA[2][128 * 32];   // [k-panel][m][k32]
    __shared__ _Float16 sB[2][128 * 32];   // [k-panel][n][k32]

    const int t = threadIdx.x;
    const int w = t >> 6;
    const int l = t & 63;

    const _Float16* gA = W + (size_t)b * wbs
                           + ((size_t)(m0 + w * 32 + (l >> 2))) * DIM + (l & 3) * 8;
    const _Float16* gB = Xt + ((size_t)b * HW + n0 + w * 32 + (l >> 2)) * DIM + (l & 3) * 8;
    const int lofs = (w * 32) * 32;

    f32x4 acc[4][4];
    #pragma unroll
    for (int i = 0; i < 4; ++i)
        #pragma unroll
        for (int j = 0; j < 4; ++j)
            acc[i][j] = (f32x4){0.f, 0.f, 0.f, 0.f};

    const int wm = (w >> 1) * 64, wn = (w & 1) * 64;
    const int fr = l & 15, fk = (l >> 4) * 8;

    for (int k0 = 0; k0 < DIM; k0 += 64) {
        __syncthreads();
        GLOBAL_TO_LDS16(gA + k0,                 &sA[0][lofs]);
        GLOBAL_TO_LDS16(gA + k0 + 16 * DIM,      &sA[0][lofs + 16 * 32]);
        GLOBAL_TO_LDS16(gA + k0 + 32,            &sA[1][lofs]);
        GLOBAL_TO_LDS16(gA + k0 + 32 + 16 * DIM, &sA[1][lofs + 16 * 32]);
        GLOBAL_TO_LDS16(gB + k0,                 &sB[0][lofs]);
        GLOBAL_TO_LDS16(gB + k0 + 16 * DIM,      &sB[0][lofs + 16 * 32]);
        GLOBAL_TO_LDS16(gB + k0 + 32,            &sB[1][lofs]);
        GLOBAL_TO_LDS16(gB + k0 + 32 + 16 * DIM, &sB[1][lofs + 16 * 32]);
        __syncthreads();

        #pragma unroll
        for (int ks = 0; ks < 2; ++ks) {
            f16x8 af[4], bfv[4];
            #pragma unroll
            for (int mi = 0; mi < 4; ++mi)
                af[mi] = *(const f16x8*)&sA[ks][(wm + mi * 16 + fr) * 32 + fk];
            #pragma unroll
            for (int ni = 0; ni < 4; ++ni)
                bfv[ni] = *(const f16x8*)&sB[ks][(wn + ni * 16 + fr) * 32 + fk];
            #pragma unroll
            for (int mi = 0; mi < 4; ++mi)
                #pragma unroll
                for (int ni = 0; ni < 4; ++ni)
                    acc[mi][ni] = __builtin_amdgcn_mfma_f32_16x16x32_f16(
                        af[mi], bfv[ni], acc[mi][ni], 0, 0, 0);
        }
    }

    const int er = (l >> 4) * 4;   // C/D: col=l&15, row=(l>>4)*4+r
    if (out_f32) {
        float* Yp = (float*)Y + (size_t)b * M * HW;
        #pragma unroll
        for (int mi = 0; mi < 4; ++mi)
            #pragma unroll
            for (int ni = 0; ni < 4; ++ni)
                #pragma unroll
                for (int r = 0; r < 4; ++r)
                    Yp[(size_t)(m0 + wm + mi * 16 + er + r) * HW + n0 + wn + ni * 16 + fr]
                        = acc[mi][ni][r];
    } else {
        _Float16* Yp = (_Float16*)Y + (size_t)b * M * HW;
        #pragma unroll
        for (int mi = 0; mi < 4; ++mi)
            #pragma unroll
            for (int ni = 0; ni < 4; ++ni)
                #pragma unroll
                for (int r = 0; r < 4; ++r)
                    Yp[(size_t)(m0 + wm + mi * 16 + er + r) * HW + n0 + wn + ni * 16 + fr]
                        = (_Float16)acc[mi][ni][r];
    }
}

// ------- depthwise 3x3 SAME over all 1152 qkv planes, fp16 io, LDS-tiled -------
// plane p = b*1152 + c; group g = c/384 selects output buffer (q->oq, k->ok, v->ov).
// ss accumulate for q,k groups only (c < 768) -- block-uniform branch.
__global__ __launch_bounds__(256) void dwconv_all(
    const _Float16* __restrict__ in, const float* __restrict__ w9,
    _Float16* __restrict__ oq, _Float16* __restrict__ ok_,
    _Float16* __restrict__ ov, float* __restrict__ ss)
{
    const int j  = blockIdx.x & 3;
    const int p  = blockIdx.x >> 2;        // b*1152 + c
    const int c  = p % 1152;
    const int b  = p / 1152;
    const int r0 = j * 32;

    __shared__ __align__(16) _Float16 tile[34 * 136 + 8];   // 4632 halfs
    const int t = threadIdx.x;

    const uint4 z4 = make_uint4(0, 0, 0, 0);
    for (int i = t; i < 579; i += 256)
        *(uint4*)&tile[i * 8] = z4;
    __syncthreads();

    const _Float16* ip = in + (size_t)p * HW;
    for (int cc = t; cc < 34 * 16; cc += 256) {
        const int i = cc >> 4, seg = cc & 15;
        const int g = r0 - 1 + i;
        if ((unsigned)g < 128u)
            *(f16x8*)&tile[i * 136 + 8 + seg * 8] = *(const f16x8*)&ip[g * 128 + seg * 8];
    }

    float w[9];
    #pragma unroll
    for (int i = 0; i < 9; ++i) w[i] = w9[c * 9 + i];
    __syncthreads();

    const int yr = t >> 3;            // 0..31
    const int xc = (t & 7) * 16;      // 0..112

    float acc[16];
    #pragma unroll
    for (int cc = 0; cc < 16; ++cc) acc[cc] = 0.f;

    #pragma unroll
    for (int dy = 0; dy < 3; ++dy) {
        const _Float16* rp = &tile[(yr + dy) * 136 + xc];
        const f16x8 v0 = *(const f16x8*)&rp[0];
        const f16x8 v1 = *(const f16x8*)&rp[8];
        const f16x8 v2 = *(const f16x8*)&rp[16];
        const f16x8 v3 = *(const f16x8*)&rp[24];
        float rv[18];
        #pragma unroll
        for (int i = 0; i < 18; ++i) {
            const int idx = 7 + i;    // LDS cols xc+7 .. xc+24 = global cols xc-1 .. xc+16
            const _Float16 h = (idx < 8)  ? v0[idx]
                             : (idx < 16) ? v1[idx - 8]
                             : (idx < 24) ? v2[idx - 16]
                                          : v3[idx - 24];
            rv[i] = (float)h;
        }
        const float w0 = w[dy * 3 + 0], w1 = w[dy * 3 + 1], w2 = w[dy * 3 + 2];
        #pragma unroll
        for (int cc = 0; cc < 16; ++cc) {
            acc[cc] = fmaf(rv[cc],     w0, acc[cc]);
            acc[cc] = fmaf(rv[cc + 1], w1, acc[cc]);
            acc[cc] = fmaf(rv[cc + 2], w2, acc[cc]);
        }
    }

    alignas(16) _Float16 oh[16];
    float ssum = 0.f;
    #pragma unroll
    for (int cc = 0; cc < 16; ++cc) {
        oh[cc] = (_Float16)acc[cc];
        ssum = fmaf(acc[cc], acc[cc], ssum);
    }
    const int grp = c / 384;
    const int cl  = c - grp * 384;
    _Float16* obase = (grp == 0) ? oq : (grp == 1) ? ok_ : ov;
    _Float16* op = obase + ((size_t)b * DIM + cl) * HW + (r0 + yr) * 128 + xc;
    *(f16x8*)&op[0] = *(const f16x8*)&oh[0];
    *(f16x8*)&op[8] = *(const f16x8*)&oh[8];

    if (c < 768) {                         // q,k groups: sumsq for normalization
        __syncthreads();                   // all tile reads done; reuse LDS
        float* red = (float*)tile;
        red[t] = ssum;
        __syncthreads();
        for (int s = 128; s > 0; s >>= 1) {
            if (t < s) red[t] += red[t + s];
            __syncthreads();
        }
        if (t == 0) atomicAdd(&ss[b * (2 * DIM) + c], red[0]);
    }
}

// ------------- raw gram G[b,h,c,d] = sum_n q[c,n]*k[d,n], fp16 in, MFMA split-K -------------
#define GNC 1024
__global__ __launch_bounds__(256) void gram_qk(
    const _Float16* __restrict__ qA, const _Float16* __restrict__ kA,
    float* __restrict__ G)
{
    const int n0 = blockIdx.x * GNC;
    const int h  = blockIdx.y;
    const int b  = blockIdx.z;
    const _Float16* qb = qA + ((size_t)b * DIM + h * CPH) * HW + n0;
    const _Float16* kb = kA + ((size_t)b * DIM + h * CPH) * HW + n0;

    const int t = threadIdx.x;
    const int w = t >> 6, l = t & 63;
    const int fr = l & 15, fk = (l >> 4) * 8;

    f32x4 acc[3][3];
    #pragma unroll
    for (int i = 0; i < 3; ++i)
        #pragma unroll
        for (int j = 0; j < 3; ++j)
            acc[i][j] = (f32x4){0.f, 0.f, 0.f, 0.f};

    const int nbase = w * (GNC / 4);    // 256 cols of n per wave
    #pragma unroll 4
    for (int nn = 0; nn < GNC / 4; nn += 32) {
        f16x8 qf[3], kf[3];
        #pragma unroll
        for (int i = 0; i < 3; ++i) {
            const size_t off = (size_t)(i * 16 + fr) * HW + nbase + nn + fk;
            qf[i] = *(const f16x8*)&qb[off];
            kf[i] = *(const f16x8*)&kb[off];
        }
        #pragma unroll
        for (int i = 0; i < 3; ++i)
            #pragma unroll
            for (int j = 0; j < 3; ++j)
                acc[i][j] = __builtin_amdgcn_mfma_f32_16x16x32_f16(
                    qf[i], kf[j], acc[i][j], 0, 0, 0);
    }

    // block-level reduce across the 4 waves in LDS, then one atomicAdd per element
    __shared__ float red[4][CPH * CPH];   // 36 KB
    const int er = (l >> 4) * 4;
    #pragma unroll
    for (int i = 0; i < 3; ++i)
        #pragma unroll
        for (int j = 0; j < 3; ++j)
            #pragma unroll
            for (int r = 0; r < 4; ++r)
                red[w][(i * 16 + er + r) * CPH + j * 16 + fr] = acc[i][j][r];
    __syncthreads();

    float* Gp = G + ((size_t)(b * NHEADS + h)) * CPH * CPH;
    for (int i = t; i < CPH * CPH; i += 256)
        atomicAdd(&Gp[i], red[0][i] + red[1][i] + red[2][i] + red[3][i]);
}

// ------------- normalize + 4x top-k softmax combined into one P (one wave per row) -------------
__global__ __launch_bounds__(64) void topk_combine(
    const float* __restrict__ G, const float* __restrict__ ss,
    const float* __restrict__ temp,
    const float* __restrict__ a1, const float* __restrict__ a2,
    const float* __restrict__ a3, const float* __restrict__ a4,
    float* __restrict__ P)
{
    const int row = blockIdx.x;           // bh*48 + r
    const int bh  = row / CPH;
    const int r   = row - bh * CPH;
    const int b = bh >> 3, h = bh & 7;
    const int l = threadIdx.x;

    const float tpr = temp[h];
    const float* ssb = ss + b * (2 * DIM);
    const float invq = 1.f / sqrtf(ssb[h * CPH + r]);

    float att = -3.0e38f;
    if (l < CPH)
        att = G[(size_t)row * CPH + l] * invq * (1.f / sqrtf(ssb[DIM + h * CPH + l])) * tpr;

    int cnt = 0;                          // # strictly greater
    #pragma unroll
    for (int i = 0; i < CPH; ++i)
        cnt += (__shfl(att, i) > att) ? 1 : 0;

    const float mx   = wave_max(att);
    const float thr0 = wave_min((l < CPH && cnt < 24) ? att : 3.0e38f);
    const float thr1 = wave_min((l < CPH && cnt < 32) ? att : 3.0e38f);
    const float thr2 = wave_min((l < CPH && cnt < 36) ? att : 3.0e38f);
    const float thr3 = wave_min((l < CPH && cnt < 38) ? att : 3.0e38f);

    const float e = (l < CPH) ? expf(att - mx) : 0.f;
    const float Z0 = wave_sum(att >= thr0 ? e : 0.f);
    const float Z1 = wave_sum(att >= thr1 ? e : 0.f);
    const float Z2 = wave_sum(att >= thr2 ? e : 0.f);
    const float Z3 = wave_sum(att >= thr3 ? e : 0.f);

    const float w0 = a1[0] / Z0, w1 = a2[0] / Z1, w2 = a3[0] / Z2, w3 = a4[0] / Z3;
    float pv = 0.f;
    if (att >= thr0) pv += w0 * e;
    if (att >= thr1) pv += w1 * e;
    if (att >= thr2) pv += w2 * e;
    if (att >= thr3) pv += w3 * e;
    if (l < CPH) P[(size_t)row * CPH + l] = pv;
}

// ------------- fused projection weight: Wf[b][o][h*48+d] = sum_c pw[o][h*48+c]*P[b,h,c,d] ----
// grid (DIM/48, NHEADS, nb) = 256 blocks; P tile + pw tile staged in LDS,
// 9 independent LDS-fed dot products per thread. Same c-summation order as before
// (bit-identical Wf).
__global__ __launch_bounds__(256) void fuse_pw(
    const float* __restrict__ pw, const float* __restrict__ P,
    _Float16* __restrict__ Wf)
{
    const int o0 = blockIdx.x * CPH;
    const int h  = blockIdx.y;
    const int b  = blockIdx.z;
    const int t  = threadIdx.x;

    __shared__ float sP[CPH][CPH];        // [c][d]
    __shared__ float sW[CPH][CPH + 1];    // [o][c]
    for (int i = t; i < CPH * CPH; i += 256) {
        const int r = i / CPH, cc = i % CPH;
        sP[r][cc] = P[((size_t)(b * NHEADS + h)) * CPH * CPH + i];
        sW[r][cc] = pw[(size_t)(o0 + r) * DIM + h * CPH + cc];
    }
    __syncthreads();

    for (int i = t; i < CPH * CPH; i += 256) {
        const int o = i / CPH, d = i % CPH;
        float s = 0.f;
        #pragma unroll
        for (int c = 0; c < CPH; ++c)
            s = fmaf(sW[o][c], sP[c][d], s);
        Wf[((size_t)b * DIM + o0 + o) * DIM + h * CPH + d] = (_Float16)s;
    }
}

extern "C" void kernel_launch(void* const* d_in, const int* in_sizes, int n_in,
                              void* d_out, int out_size, void* d_ws, size_t ws_size,
                              hipStream_t stream)
{
    const float* x      = (const float*)d_in[0];
    const float* qkv_w  = (const float*)d_in[1];
    const float* dw_w   = (const float*)d_in[2];
    const float* proj_w = (const float*)d_in[3];
    const float* temp   = (const float*)d_in[4];
    const float* a1 = (const float*)d_in[5];
    const float* a2 = (const float*)d_in[6];
    const float* a3 = (const float*)d_in[7];
    const float* a4 = (const float*)d_in[8];
    float* out = (float*)d_out;

    const size_t PBE = (size_t)HW * DIM;        // per-batch elems (6,291,456)
    const size_t WQE = (size_t)1152 * 384;
    const size_t WPE = (size_t)384 * 384;

    // regions: A(1) + C(3) + D(1) + E(1) + F(1) = 7*PBE fp16 per batch
    auto need_for = [&](size_t nb) -> size_t {
        return nb * PBE * 2 * 7 + (WQE + nb * WPE) * 2
             + (nb * 768 + 2 * nb * NHEADS * CPH * CPH) * 4;
    };

    int nb, npass;
    if      (ws_size >= need_for(4)) { nb = 4; npass = 1; }
    else if (ws_size >= need_for(2)) { nb = 2; npass = 2; }
    else if (ws_size >= need_for(1)) { nb = 1; npass = 4; }
    else return;

    _Float16* A  = (_Float16*)d_ws;             // xt -> vt [nb][HW][384]
    _Float16* C  = A + (size_t)nb * PBE;        // raw qkv [nb][1152][HW]
    _Float16* D  = C + (size_t)3 * nb * PBE;    // q~
    _Float16* E  = D + (size_t)nb * PBE;        // k~
    _Float16* F  = E + (size_t)nb * PBE;        // v~
    _Float16* wq = F + (size_t)nb * PBE;        // qkv_w fp16 [1152][384]
    _Float16* Wf = wq + WQE;                    // fused proj weight [nb][384][384]
    float* buf_ss = (float*)(Wf + (size_t)nb * WPE);          // [nb][768]
    float* buf_G  = buf_ss + (size_t)nb * 768;                // [nb][8][48][48]
    float* buf_P  = buf_G + (size_t)nb * NHEADS * CPH * CPH;

    cvt_w<<<dim3((1152 * 384 + 255) / 256), 256, 0, stream>>>(qkv_w, wq, 1152 * 384);

    for (int p = 0; p < npass; ++p) {
        const int b0 = p * nb;
        const float* xp   = x   + (size_t)b0 * PBE;
        float*       outp = out + (size_t)b0 * PBE;

        transpose_cvt<<<dim3(HW / 64, 2, nb), 256, 0, stream>>>(xp, A);
        // zero ss + G (contiguous) — dwconv and gram accumulate atomically
        hipMemsetAsync(buf_ss, 0,
                       ((size_t)nb * 768 + (size_t)nb * NHEADS * CPH * CPH) * sizeof(float),
                       stream);

        // merged qkv GEMM: [1152][384] @ xt -> C (fp16, NCHW per 1152-plane group)
        gemm_f16<<<dim3(HW / 128, 1152 / 128, nb), 256, 0, stream>>>(wq, A, C, 0, 0);

        // merged depthwise over all 1152 planes; q->D, k->E, v->F; ss for q,k
        dwconv_all<<<dim3(nb * 1152 * 4), 256, 0, stream>>>(C, dw_w, D, E, F, buf_ss);

        gram_qk<<<dim3(HW / GNC, NHEADS, nb), 256, 0, stream>>>(D, E, buf_G);
        topk_combine<<<dim3(nb * NHEADS * CPH), 64, 0, stream>>>(
            buf_G, buf_ss, temp, a1, a2, a3, a4, buf_P);

        // fused proj weight (pw @ P per head/batch)
        fuse_pw<<<dim3(DIM / CPH, NHEADS, nb), 256, 0, stream>>>(proj_w, buf_P, Wf);

        // v~ -> vt (Xt layout); xt in A dead after merged GEMM
        transpose16<<<dim3(HW / 128, 2, nb), 256, 0, stream>>>(F, A);

        // fused PV+proj: out = Wf_b @ vt, fp32 out
        gemm_f16<<<dim3(HW / 128, DIM / 128, nb), 256, 0, stream>>>(Wf, A, outp, 1, (int)WPE);
    }
}